// Round 4
// baseline (84.608 us; speedup 1.0000x reference)
//
#include <hip/hip_runtime.h>

// GroupStratifiedSurvivalLoss: per-sample Weibull NLL + mean + 16 group means.
// R3: latency/stall attack. Block-chunked contiguous access (4KB iter stride,
// not 8MB grid-stride jumps), 2x unrolled loads for MLP, ballot-based counts
// (SALU, reuses the sum path's v_cmp, halves the butterfly epilogue).

namespace {
constexpr int NG = 16;       // number of groups
constexpr int BLOCK = 256;   // threads per block (4 waves)
constexpr float LOG2E = 1.4426950408889634f;
constexpr float LN2   = 0.6931471805599453f;
}

__device__ __forceinline__ float flog2(float x) { return __builtin_amdgcn_logf(x); }
__device__ __forceinline__ float fexp2(float x) { return __builtin_amdgcn_exp2f(x); }
__device__ __forceinline__ float frcp(float x)  { return __builtin_amdgcn_rcpf(x); }

// per-sample NLL: h1 - u * log(exp(h1-h0) - 1), h1=(y+1/a)^b, h0=y^b
__device__ __forceinline__ float per_sample(float b, float a, float y, float u) {
    const float inva = frcp(a);
    const float h1 = fexp2(b * flog2(y + inva));
    const float h0 = fexp2(b * flog2(y));
    const float em1 = fexp2((h1 - h0) * LOG2E) - 1.0f;   // exp(d)-1, d >= ~0.13
    const float t = flog2(em1) * LN2;                     // log(exp(d)-1)
    return __builtin_fmaf(-u, t, h1);                     // h1 - u*t
}

__global__ __launch_bounds__(BLOCK) void gssl_main_kernel(
    const float* __restrict__ bptr,   // shape
    const float* __restrict__ aptr,   // scale
    const float* __restrict__ yptr,   // time
    const float* __restrict__ uptr,   // event
    const int*   __restrict__ gptr,   // group
    float* __restrict__ ws,           // ws[0..15]=gsum, ws[16..31]=gcnt
    int per_block, int n4, int n)
{
    __shared__ float sbin[2 * NG];
    const int tid = threadIdx.x;
    if (tid < 2 * NG) sbin[tid] = 0.0f;
    __syncthreads();

    // Per-thread register sum bins; wave-uniform counts (each lane holds the
    // identical wave-total popcount). ALL indices compile-time.
    float asum[NG];
    int   acnt[NG];
    #pragma unroll
    for (int q = 0; q < NG; ++q) { asum[q] = 0.0f; acnt[q] = 0; }

    const int base = blockIdx.x * per_block;       // float4 units
    const int rem  = n4 - base;
    const int jend = (rem < per_block) ? (rem < 0 ? 0 : rem) : per_block;

    // Process one float4-group of 4 samples into the register bins.
    auto do4 = [&](int i) {
        const float4 b4 = reinterpret_cast<const float4*>(bptr)[i];
        const float4 a4 = reinterpret_cast<const float4*>(aptr)[i];
        const float4 y4 = reinterpret_cast<const float4*>(yptr)[i];
        const float4 u4 = reinterpret_cast<const float4*>(uptr)[i];
        const int4   g4 = reinterpret_cast<const int4*>(gptr)[i];
        const float bb[4] = {b4.x, b4.y, b4.z, b4.w};
        const float aa[4] = {a4.x, a4.y, a4.z, a4.w};
        const float yy[4] = {y4.x, y4.y, y4.z, y4.w};
        const float uu[4] = {u4.x, u4.y, u4.z, u4.w};
        const int   gg[4] = {g4.x, g4.y, g4.z, g4.w};
        #pragma unroll
        for (int k = 0; k < 4; ++k) {
            const float ps = per_sample(bb[k], aa[k], yy[k], uu[k]);
            const int g = gg[k];
            #pragma unroll
            for (int q = 0; q < NG; ++q) {
                const bool eq = (g == q);
                asum[q] += eq ? ps : 0.0f;               // v_cmp + cndmask + add
                acnt[q] += (int)__popcll(__ballot(eq));  // wave-total, SALU-friendly
            }
        }
    };

    // 2x-unrolled chunk loop: two independent float4 groups in flight.
    int j = tid;
    for (; j + BLOCK < jend; j += 2 * BLOCK) {
        do4(base + j);
        do4(base + j + BLOCK);
    }
    if (j < jend) do4(base + j);

    // Wave-level butterfly reduction of sums (counts already wave-uniform).
    #pragma unroll
    for (int q = 0; q < NG; ++q) {
        #pragma unroll
        for (int off = 32; off > 0; off >>= 1)
            asum[q] += __shfl_xor(asum[q], off, 64);
    }

    // One lane per wave folds into block bins.
    if ((tid & 63) == 0) {
        #pragma unroll
        for (int q = 0; q < NG; ++q) {
            atomicAdd(&sbin[q], asum[q]);
            atomicAdd(&sbin[NG + q], (float)acnt[q]);
        }
    }
    __syncthreads();

    // Block -> global: 32 atomics per block.
    if (tid < 2 * NG) atomicAdd(&ws[tid], sbin[tid]);

    // Tail (n not divisible by 4) — N=2^24 so this is empty, kept for safety.
    if (blockIdx.x == 0 && tid == 0) {
        for (int i = n4 * 4; i < n; ++i) {
            const float ps = per_sample(bptr[i], aptr[i], yptr[i], uptr[i]);
            atomicAdd(&ws[gptr[i]], ps);
            atomicAdd(&ws[NG + gptr[i]], 1.0f);
        }
    }
}

__global__ __launch_bounds__(64) void gssl_final_kernel(
    const float* __restrict__ ws, float* __restrict__ out, float invN)
{
    const int t = threadIdx.x;
    if (t < NG) {
        const float gs = ws[t];
        const float gc = ws[NG + t];
        out[1 + t] = gs / fmaxf(gc, 1.0f);
    }
    // loss = (sum over groups of gsum) / N
    float v = (t < NG) ? ws[t] : 0.0f;
    #pragma unroll
    for (int off = 32; off > 0; off >>= 1) v += __shfl_down(v, off);
    if (t == 0) out[0] = v * invN;
}

extern "C" void kernel_launch(void* const* d_in, const int* in_sizes, int n_in,
                              void* d_out, int out_size, void* d_ws, size_t ws_size,
                              hipStream_t stream) {
    const float* shape_p = (const float*)d_in[0];
    const float* scale_p = (const float*)d_in[1];
    const float* time_p  = (const float*)d_in[2];
    const float* event_p = (const float*)d_in[3];
    // d_in[4] = lengths: only its length (== n) is used by the reference.
    const int*   group_p = (const int*)d_in[5];
    float* out = (float*)d_out;
    float* ws  = (float*)d_ws;

    const int n  = in_sizes[0];
    const int n4 = n >> 2;

    // ws is poisoned 0xAA and never re-poisoned between replays: zero it every call.
    hipMemsetAsync(ws, 0, 2 * NG * sizeof(float), stream);

    const int blocks = 2048;
    const int per_block = (n4 + blocks - 1) / blocks;   // float4s per block chunk

    hipLaunchKernelGGL(gssl_main_kernel, dim3(blocks), dim3(BLOCK), 0, stream,
                       shape_p, scale_p, time_p, event_p, group_p, ws,
                       per_block, n4, n);
    hipLaunchKernelGGL(gssl_final_kernel, dim3(1), dim3(64), 0, stream,
                       ws, out, 1.0f / (float)n);
}

// Round 5
// 80.339 us; speedup vs baseline: 1.0531x; 1.0531x over previous
//
#include <hip/hip_runtime.h>

// GroupStratifiedSurvivalLoss: per-sample Weibull NLL + mean + 16 group means.
// R4: register-starved MLP fix. R3 showed VGPR=32 -> compiler serialized the
// 5 float4 loads per iteration (nothing saturated: VALU 30%, HBM 17%).
// Explicit 2-stage software pipeline (load next group before computing current)
// + __launch_bounds__(256,4) to allow up to 128 VGPRs.

namespace {
constexpr int NG = 16;       // number of groups
constexpr int BLOCK = 256;   // threads per block (4 waves)
constexpr float LOG2E = 1.4426950408889634f;
constexpr float LN2   = 0.6931471805599453f;
}

__device__ __forceinline__ float flog2(float x) { return __builtin_amdgcn_logf(x); }
__device__ __forceinline__ float fexp2(float x) { return __builtin_amdgcn_exp2f(x); }
__device__ __forceinline__ float frcp(float x)  { return __builtin_amdgcn_rcpf(x); }

// per-sample NLL: h1 - u * log(exp(h1-h0) - 1), h1=(y+1/a)^b, h0=y^b
__device__ __forceinline__ float per_sample(float b, float a, float y, float u) {
    const float inva = frcp(a);
    const float h1 = fexp2(b * flog2(y + inva));
    const float h0 = fexp2(b * flog2(y));
    const float em1 = fexp2((h1 - h0) * LOG2E) - 1.0f;   // exp(d)-1, d >= ~0.13
    const float t = flog2(em1) * LN2;                     // log(exp(d)-1)
    return __builtin_fmaf(-u, t, h1);                     // h1 - u*t
}

struct Grp { float4 b, a, y, u; int4 g; };   // 20 VGPRs of payload

__global__ __launch_bounds__(BLOCK, 4) void gssl_main_kernel(
    const float* __restrict__ bptr,   // shape
    const float* __restrict__ aptr,   // scale
    const float* __restrict__ yptr,   // time
    const float* __restrict__ uptr,   // event
    const int*   __restrict__ gptr,   // group
    float* __restrict__ ws,           // ws[0..15]=gsum, ws[16..31]=gcnt
    int per_block, int n4, int n)
{
    __shared__ float sbin[2 * NG];
    const int tid = threadIdx.x;
    if (tid < 2 * NG) sbin[tid] = 0.0f;
    __syncthreads();

    // Per-thread register sum bins; wave-uniform SALU counts. Compile-time idx.
    float asum[NG];
    int   acnt[NG];
    #pragma unroll
    for (int q = 0; q < NG; ++q) { asum[q] = 0.0f; acnt[q] = 0; }

    const int base = blockIdx.x * per_block;       // float4 units
    const int rem  = n4 - base;
    const int jend = (rem < per_block) ? (rem < 0 ? 0 : rem) : per_block;

    auto ld = [&](int i) {
        Grp r;
        r.b = reinterpret_cast<const float4*>(bptr)[i];
        r.a = reinterpret_cast<const float4*>(aptr)[i];
        r.y = reinterpret_cast<const float4*>(yptr)[i];
        r.u = reinterpret_cast<const float4*>(uptr)[i];
        r.g = reinterpret_cast<const int4*>(gptr)[i];
        return r;
    };

    auto compute = [&](const Grp& G) {
        const float bb[4] = {G.b.x, G.b.y, G.b.z, G.b.w};
        const float aa[4] = {G.a.x, G.a.y, G.a.z, G.a.w};
        const float yy[4] = {G.y.x, G.y.y, G.y.z, G.y.w};
        const float uu[4] = {G.u.x, G.u.y, G.u.z, G.u.w};
        const int   gg[4] = {G.g.x, G.g.y, G.g.z, G.g.w};
        #pragma unroll
        for (int k = 0; k < 4; ++k) {
            const float ps = per_sample(bb[k], aa[k], yy[k], uu[k]);
            const int g = gg[k];
            #pragma unroll
            for (int q = 0; q < NG; ++q) {
                const bool eq = (g == q);
                asum[q] += eq ? ps : 0.0f;               // v_cmp + cndmask + add
                acnt[q] += (int)__popcll(__ballot(eq));  // wave-total, SALU
            }
        }
    };

    // 2-stage software pipeline: next iteration's 5 loads are in flight
    // while the current iteration computes (~600 VALU cycles of cover).
    int j = tid;
    if (j < jend) {
        Grp cur = ld(base + j);
        for (; j + BLOCK < jend; j += BLOCK) {
            Grp nxt = ld(base + j + BLOCK);   // issue 5 loads
            compute(cur);                     // ~600 cycles of latency cover
            cur = nxt;
        }
        compute(cur);
    }

    // Wave-level butterfly reduction of sums (counts already wave-uniform).
    #pragma unroll
    for (int q = 0; q < NG; ++q) {
        #pragma unroll
        for (int off = 32; off > 0; off >>= 1)
            asum[q] += __shfl_xor(asum[q], off, 64);
    }

    // One lane per wave folds into block bins.
    if ((tid & 63) == 0) {
        #pragma unroll
        for (int q = 0; q < NG; ++q) {
            atomicAdd(&sbin[q], asum[q]);
            atomicAdd(&sbin[NG + q], (float)acnt[q]);
        }
    }
    __syncthreads();

    // Block -> global: 32 atomics per block.
    if (tid < 2 * NG) atomicAdd(&ws[tid], sbin[tid]);

    // Tail (n not divisible by 4) — N=2^24 so this is empty, kept for safety.
    if (blockIdx.x == 0 && tid == 0) {
        for (int i = n4 * 4; i < n; ++i) {
            const float ps = per_sample(bptr[i], aptr[i], yptr[i], uptr[i]);
            atomicAdd(&ws[gptr[i]], ps);
            atomicAdd(&ws[NG + gptr[i]], 1.0f);
        }
    }
}

__global__ __launch_bounds__(64) void gssl_final_kernel(
    const float* __restrict__ ws, float* __restrict__ out, float invN)
{
    const int t = threadIdx.x;
    if (t < NG) {
        const float gs = ws[t];
        const float gc = ws[NG + t];
        out[1 + t] = gs / fmaxf(gc, 1.0f);
    }
    // loss = (sum over groups of gsum) / N
    float v = (t < NG) ? ws[t] : 0.0f;
    #pragma unroll
    for (int off = 32; off > 0; off >>= 1) v += __shfl_down(v, off);
    if (t == 0) out[0] = v * invN;
}

extern "C" void kernel_launch(void* const* d_in, const int* in_sizes, int n_in,
                              void* d_out, int out_size, void* d_ws, size_t ws_size,
                              hipStream_t stream) {
    const float* shape_p = (const float*)d_in[0];
    const float* scale_p = (const float*)d_in[1];
    const float* time_p  = (const float*)d_in[2];
    const float* event_p = (const float*)d_in[3];
    // d_in[4] = lengths: only its length (== n) is used by the reference.
    const int*   group_p = (const int*)d_in[5];
    float* out = (float*)d_out;
    float* ws  = (float*)d_ws;

    const int n  = in_sizes[0];
    const int n4 = n >> 2;

    // ws is poisoned 0xAA and never re-poisoned between replays: zero it every call.
    hipMemsetAsync(ws, 0, 2 * NG * sizeof(float), stream);

    const int blocks = 2048;
    const int per_block = (n4 + blocks - 1) / blocks;   // float4s per block chunk

    hipLaunchKernelGGL(gssl_main_kernel, dim3(blocks), dim3(BLOCK), 0, stream,
                       shape_p, scale_p, time_p, event_p, group_p, ws,
                       per_block, n4, n);
    hipLaunchKernelGGL(gssl_final_kernel, dim3(1), dim3(64), 0, stream,
                       ws, out, 1.0f / (float)n);
}

// Round 6
// 73.172 us; speedup vs baseline: 1.1563x; 1.0979x over previous
//
#include <hip/hip_runtime.h>

// GroupStratifiedSurvivalLoss: per-sample Weibull NLL + mean + 16 group means.
// R5: binning moved from 16-way register select-accumulate (~80 issue-cyc/elem
// on the VALU) to per-thread PRIVATE LDS slots (stride 17 -> ~2-way banks,
// no atomics): ~23 cyc on the LDS pipe, overlapped with trans + VMEM.
// R2-R4 plateau at ~80us was instruction-issue on the binning, not memory.

namespace {
constexpr int NG = 16;       // number of groups
constexpr int BLOCK = 256;   // threads per block (4 waves)
constexpr int ST = NG + 1;   // slot stride (17) -> conflict-free-ish banks
constexpr float LOG2E = 1.4426950408889634f;
constexpr float LN2   = 0.6931471805599453f;
}

__device__ __forceinline__ float flog2(float x) { return __builtin_amdgcn_logf(x); }
__device__ __forceinline__ float fexp2(float x) { return __builtin_amdgcn_exp2f(x); }
__device__ __forceinline__ float frcp(float x)  { return __builtin_amdgcn_rcpf(x); }

// per-sample NLL: h1 - u * log(exp(h1-h0) - 1), h1=(y+1/a)^b, h0=y^b
__device__ __forceinline__ float per_sample(float b, float a, float y, float u) {
    const float inva = frcp(a);
    const float h1 = fexp2(b * flog2(y + inva));
    const float h0 = fexp2(b * flog2(y));
    const float em1 = fexp2((h1 - h0) * LOG2E) - 1.0f;   // exp(d)-1, d >= ~0.13
    const float t = flog2(em1) * LN2;                     // log(exp(d)-1)
    return __builtin_fmaf(-u, t, h1);                     // h1 - u*t
}

struct Grp { float4 b, a, y, u; int4 g; };

__global__ __launch_bounds__(BLOCK, 4) void gssl_main_kernel(
    const float* __restrict__ bptr,   // shape
    const float* __restrict__ aptr,   // scale
    const float* __restrict__ yptr,   // time
    const float* __restrict__ uptr,   // event
    const int*   __restrict__ gptr,   // group
    float* __restrict__ ws,           // ws[0..15]=gsum, ws[16..31]=gcnt
    int per_block, int n4, int n)
{
    __shared__ float lsum[BLOCK * ST];   // 17 KB, per-thread private rows
    __shared__ float lcnt[BLOCK * ST];   // 17 KB
    __shared__ float sbin[2 * NG];
    const int tid = threadIdx.x;
    const int myrow = tid * ST;

    #pragma unroll
    for (int q = 0; q < ST; ++q) { lsum[myrow + q] = 0.0f; lcnt[myrow + q] = 0.0f; }
    if (tid < 2 * NG) sbin[tid] = 0.0f;
    // Slots are thread-private: no sync needed until the epilogue.

    const int base = blockIdx.x * per_block;       // float4 units
    const int rem  = n4 - base;
    const int jend = (rem < per_block) ? (rem < 0 ? 0 : rem) : per_block;

    auto ld = [&](int i) {
        Grp r;
        r.b = reinterpret_cast<const float4*>(bptr)[i];
        r.a = reinterpret_cast<const float4*>(aptr)[i];
        r.y = reinterpret_cast<const float4*>(yptr)[i];
        r.u = reinterpret_cast<const float4*>(uptr)[i];
        r.g = reinterpret_cast<const int4*>(gptr)[i];
        return r;
    };

    auto do4 = [&](const Grp& G) {
        const float bb[4] = {G.b.x, G.b.y, G.b.z, G.b.w};
        const float aa[4] = {G.a.x, G.a.y, G.a.z, G.a.w};
        const float yy[4] = {G.y.x, G.y.y, G.y.z, G.y.w};
        const float uu[4] = {G.u.x, G.u.y, G.u.z, G.u.w};
        const int   gg[4] = {G.g.x, G.g.y, G.g.z, G.g.w};
        #pragma unroll
        for (int k = 0; k < 4; ++k) {
            const float ps = per_sample(bb[k], aa[k], yy[k], uu[k]);
            const int off = myrow + gg[k];
            lsum[off] += ps;     // private slot: ds_read + v_add + ds_write
            lcnt[off] += 1.0f;
        }
    };

    // 2-stage pipeline: next group's 5 loads in flight during compute.
    int j = tid;
    if (j < jend) {
        Grp cur = ld(base + j);
        for (; j + BLOCK < jend; j += BLOCK) {
            Grp nxt = ld(base + j + BLOCK);
            do4(cur);
            cur = nxt;
        }
        do4(cur);
    }
    __syncthreads();

    // Epilogue: thread t sums column q = t&15 over rows c*16..c*16+15.
    const int q = tid & 15, c = tid >> 4;
    float s = 0.0f, cnt = 0.0f;
    #pragma unroll
    for (int r = 0; r < 16; ++r) {
        const int off = (c * 16 + r) * ST + q;
        s   += lsum[off];
        cnt += lcnt[off];
    }
    // Within each wave, lanes l, l^16, l^32 hold the same bin: fold.
    s   += __shfl_xor(s, 16, 64);   s   += __shfl_xor(s, 32, 64);
    cnt += __shfl_xor(cnt, 16, 64); cnt += __shfl_xor(cnt, 32, 64);
    if ((tid & 48) == 0) {           // lanes 0..15 of each wave
        atomicAdd(&sbin[q], s);
        atomicAdd(&sbin[NG + q], cnt);
    }
    __syncthreads();

    // Block -> global: 32 atomics per block.
    if (tid < 2 * NG) atomicAdd(&ws[tid], sbin[tid]);

    // Tail (n not divisible by 4) — N=2^24 so this is empty, kept for safety.
    if (blockIdx.x == 0 && tid == 0) {
        for (int i = n4 * 4; i < n; ++i) {
            const float ps = per_sample(bptr[i], aptr[i], yptr[i], uptr[i]);
            atomicAdd(&ws[gptr[i]], ps);
            atomicAdd(&ws[NG + gptr[i]], 1.0f);
        }
    }
}

__global__ __launch_bounds__(64) void gssl_final_kernel(
    const float* __restrict__ ws, float* __restrict__ out, float invN)
{
    const int t = threadIdx.x;
    if (t < NG) {
        const float gs = ws[t];
        const float gc = ws[NG + t];
        out[1 + t] = gs / fmaxf(gc, 1.0f);
    }
    // loss = (sum over groups of gsum) / N
    float v = (t < NG) ? ws[t] : 0.0f;
    #pragma unroll
    for (int off = 32; off > 0; off >>= 1) v += __shfl_down(v, off);
    if (t == 0) out[0] = v * invN;
}

extern "C" void kernel_launch(void* const* d_in, const int* in_sizes, int n_in,
                              void* d_out, int out_size, void* d_ws, size_t ws_size,
                              hipStream_t stream) {
    const float* shape_p = (const float*)d_in[0];
    const float* scale_p = (const float*)d_in[1];
    const float* time_p  = (const float*)d_in[2];
    const float* event_p = (const float*)d_in[3];
    // d_in[4] = lengths: only its length (== n) is used by the reference.
    const int*   group_p = (const int*)d_in[5];
    float* out = (float*)d_out;
    float* ws  = (float*)d_ws;

    const int n  = in_sizes[0];
    const int n4 = n >> 2;

    // ws is poisoned 0xAA and never re-poisoned between replays: zero it every call.
    hipMemsetAsync(ws, 0, 2 * NG * sizeof(float), stream);

    const int blocks = 2048;
    const int per_block = (n4 + blocks - 1) / blocks;   // float4s per block chunk

    hipLaunchKernelGGL(gssl_main_kernel, dim3(blocks), dim3(BLOCK), 0, stream,
                       shape_p, scale_p, time_p, event_p, group_p, ws,
                       per_block, n4, n);
    hipLaunchKernelGGL(gssl_final_kernel, dim3(1), dim3(64), 0, stream,
                       ws, out, 1.0f / (float)n);
}